// Round 5
// baseline (94.287 us; speedup 1.0000x reference)
//
#include <hip/hip_runtime.h>
#include <cstdint>
#include <cstddef>

// Problem constants
#define B_    16
#define S_    1024
#define D_    512
#define P_    256
#define MAXS_ 2048

typedef unsigned short u16;
typedef unsigned int   u32;
typedef _Float16 f16;
typedef _Float16 f16x8 __attribute__((ext_vector_type(8)));
typedef float  f32x4  __attribute__((ext_vector_type(4)));
typedef unsigned short u16x4 __attribute__((ext_vector_type(4)));
typedef unsigned short u16x8 __attribute__((ext_vector_type(8)));

__device__ __forceinline__ void gld_lds16(const void* g, void* l) {
  __builtin_amdgcn_global_load_lds(
      (const __attribute__((address_space(1))) u32*)g,
      (__attribute__((address_space(3))) u32*)l, 16, 0, 0);
}

__device__ __forceinline__ u16 f2h(float f) {
  return __builtin_bit_cast(u16, (f16)f);
}
__device__ __forceinline__ float h2f(u16 h) {
  return (float)__builtin_bit_cast(f16, h);
}

// ---------------------------------------------------------------------------
// f32 -> f16 convert (data, W)
// ---------------------------------------------------------------------------
__global__ void convert_f16_kernel(const float* __restrict__ src, u16* __restrict__ dst, long n4) {
  long stride = (long)gridDim.x * blockDim.x;
  for (long i = (long)blockIdx.x * blockDim.x + threadIdx.x; i < n4; i += stride) {
    float4 v = ((const float4*)src)[i];
    u16x4 o;
    o[0] = f2h(v.x); o[1] = f2h(v.y); o[2] = f2h(v.z); o[3] = f2h(v.w);
    ((u16x4*)dst)[i] = o;
  }
}

// ---------------------------------------------------------------------------
// QK^T, slot-pipelined: C[b] = scale * A[b] (1024x512) @ A[b]^T -> f16.
//   BM=BN=256. K split into 16 slots of BK=32; LDS ring of 4 slots (32KB
//   each: A-part 16KB + B-part 16KB) = 128KB. Staging runs 3 slots ahead
//   (ring guarantees no overlap with the slot being read). 8 waves 2Mx4N,
//   wave tile 128x64 (8x4 frags). Per slot: 2 phases (m-half), each
//   {ds_reads, stage half-slot (2 gld_lds), barrier, lgkmcnt(0), setprio,
//   16 MFMA, setprio, barrier}; vmcnt(8) once per slot (2 slots in
//   flight), drain 8->4->0 over the last slots. XOR swizzle key (row>>1)&3
//   for 64B rows (<=2-way b128 conflict), source-side for gld_lds,
//   read-side on ds_read.
// ---------------------------------------------------------------------------
__global__ __launch_bounds__(512, 2) void qk_pipe(
    const u16* __restrict__ A, u16* __restrict__ Cout, float scale) {
  extern __shared__ __align__(16) char smem[];   // 4 * 32768
  const int tid  = threadIdx.x;
  const int lane = tid & 63;
  const int w    = tid >> 6;
  const int wm   = w >> 2;        // 0..1
  const int wn   = w & 3;         // 0..3
  const int lr   = lane & 15;
  const int hi   = lane >> 4;

  const int bz = blockIdx.z;
  const int I0 = blockIdx.y * 256;
  const int J0 = blockIdx.x * 256;
  const u16* Ab = A + (long)bz * (S_ * D_);

  // stage part (0=A rows from I0, 1=B rows from J0) of slot s
  auto stageP = [&](int s, int part) {
    if (s >= 16) return;
    char* dst = smem + (s & 3) * 32768 + part * 16384;
    const int base = part ? J0 : I0;
    const int k0 = s * 32;
    #pragma unroll
    for (int i = 0; i < 2; ++i) {
      int cid   = i * 512 + tid;
      int inner = cid >> 2;
      int c     = (cid & 3) ^ ((inner >> 1) & 3);   // inverse-swizzled source
      gld_lds16(Ab + (size_t)(base + inner) * D_ + k0 + c * 8, dst + cid * 16);
    }
  };

  f32x4 acc[8][4] = {};

  stageP(0, 0); stageP(0, 1);
  stageP(1, 0); stageP(1, 1);
  stageP(2, 0); stageP(2, 1);
  asm volatile("s_waitcnt vmcnt(8)" ::: "memory");   // slot 0 landed
  __builtin_amdgcn_s_barrier();

  for (int s = 0; s < 16; ++s) {
    const char* sl = smem + (s & 3) * 32768;
    f16x8 bf[4];
    // ---- phase 0 (m-half 0) ----
    {
      f16x8 af[4];
      #pragma unroll
      for (int mq = 0; mq < 4; ++mq) {
        int row = wm * 128 + mq * 16 + lr;
        int cp  = hi ^ ((row >> 1) & 3);
        af[mq] = *(const f16x8*)(sl + row * 64 + cp * 16);
      }
      #pragma unroll
      for (int n = 0; n < 4; ++n) {
        int row = wn * 64 + n * 16 + lr;
        int cp  = hi ^ ((row >> 1) & 3);
        bf[n] = *(const f16x8*)(sl + 16384 + row * 64 + cp * 16);
      }
      stageP(s + 3, 0);
      __builtin_amdgcn_s_barrier();
      asm volatile("s_waitcnt lgkmcnt(0)" ::: "memory");
      __builtin_amdgcn_sched_barrier(0);
      __builtin_amdgcn_s_setprio(1);
      #pragma unroll
      for (int mq = 0; mq < 4; ++mq)
        #pragma unroll
        for (int n = 0; n < 4; ++n)
          acc[mq][n] = __builtin_amdgcn_mfma_f32_16x16x32_f16(af[mq], bf[n], acc[mq][n], 0, 0, 0);
      __builtin_amdgcn_s_setprio(0);
      __builtin_amdgcn_s_barrier();
    }
    // ---- phase 1 (m-half 1) ----
    {
      f16x8 af[4];
      #pragma unroll
      for (int mq = 0; mq < 4; ++mq) {
        int row = wm * 128 + 64 + mq * 16 + lr;
        int cp  = hi ^ ((row >> 1) & 3);
        af[mq] = *(const f16x8*)(sl + row * 64 + cp * 16);
      }
      stageP(s + 3, 1);
      __builtin_amdgcn_s_barrier();
      asm volatile("s_waitcnt lgkmcnt(0)" ::: "memory");
      __builtin_amdgcn_sched_barrier(0);
      __builtin_amdgcn_s_setprio(1);
      #pragma unroll
      for (int mq = 0; mq < 4; ++mq)
        #pragma unroll
        for (int n = 0; n < 4; ++n)
          acc[4 + mq][n] = __builtin_amdgcn_mfma_f32_16x16x32_f16(af[mq], bf[n], acc[4 + mq][n], 0, 0, 0);
      __builtin_amdgcn_s_setprio(0);
      // once-per-slot counted wait: keeps 2 slots in flight; drains at tail
      if (s <= 12)      asm volatile("s_waitcnt vmcnt(8)" ::: "memory");
      else if (s == 13) asm volatile("s_waitcnt vmcnt(4)" ::: "memory");
      else if (s == 14) asm volatile("s_waitcnt vmcnt(0)" ::: "memory");
      __builtin_amdgcn_s_barrier();
    }
  }

  // epilogue: f16 out with scale. C/D: col = lane&15, row = (lane>>4)*4+reg.
  u16* Cb = Cout + (long)bz * S_ * S_;
  const int row0 = I0 + wm * 128;
  const int col0 = J0 + wn * 64;
  #pragma unroll
  for (int m = 0; m < 8; ++m) {
    #pragma unroll
    for (int i = 0; i < 4; ++i) {
      int r = row0 + m * 16 + (hi << 2) + i;
      #pragma unroll
      for (int n = 0; n < 4; ++n) {
        int c = col0 + n * 16 + lr;
        Cb[(size_t)r * S_ + c] = f2h(acc[m][n][i] * scale);
      }
    }
  }
}

// ---------------------------------------------------------------------------
// Fused softmax + PV + bias + tail-zero.
//   Block: 64 q-rows x full kv (K=1024) x full P (256). grid (1, 32, 16);
//   y-tiles 16..31 only zero the out rows S_..2S_-1.
//   Pass 1: per-row (max, 1/sum(exp)) from scoresH (row L2-hot for pass 2).
//   Pass 2: pipelined NT GEMM; A = P staged by reg (load f16 scores ->
//   exp2((s-m)*l2e)*invl -> swizzled ds_write); B = VWT via gld_lds.
//   8 waves 2Mx4N, wave tile 32x64. Counted vmcnt(4) -> A-write,
//   vmcnt(0)+lgkmcnt(0) -> barrier.
// ---------------------------------------------------------------------------
__global__ __launch_bounds__(512, 4) void smpv_kernel(
    const u16* __restrict__ scores, const u16* __restrict__ VWT,
    float* __restrict__ out, const float* __restrict__ bias) {
  extern __shared__ __align__(16) char smem[];   // 2 * 40960
  constexpr int SZB = 8192 + 32768;
  const int tid  = threadIdx.x;
  const int lane = tid & 63;
  const int w    = tid >> 6;
  const int bz   = blockIdx.z;
  const int yt   = blockIdx.y;

  float* ob = out + (long)bz * MAXS_ * P_;
  if (yt >= 16) {                       // zero tail rows
    float4* o = (float4*)(ob + (size_t)yt * 64 * P_);
    for (int i = tid; i < 64 * P_ / 4; i += 512)
      o[i] = make_float4(0.f, 0.f, 0.f, 0.f);
    return;
  }

  const int q0 = yt * 64;
  const u16* sb = scores + ((long)bz * S_ + q0) * S_;
  const float l2e = 1.4426950408889634f;

  // ---- pass 1: row stats ----
  float* smStat = (float*)smem;         // [64][2]
  {
    const u16* rp = sb + (size_t)(w * 8) * S_ + lane * 16;
    for (int j = 0; j < 8; ++j) {
      u16x8 a0 = *(const u16x8*)(rp + (size_t)j * S_);
      u16x8 a1 = *(const u16x8*)(rp + (size_t)j * S_ + 8);
      float v[16];
      #pragma unroll
      for (int k = 0; k < 8; ++k) { v[k] = h2f(a0[k]); v[8 + k] = h2f(a1[k]); }
      float mx = v[0];
      #pragma unroll
      for (int k = 1; k < 16; ++k) mx = fmaxf(mx, v[k]);
      #pragma unroll
      for (int off = 32; off > 0; off >>= 1) mx = fmaxf(mx, __shfl_xor(mx, off));
      float sum = 0.f;
      #pragma unroll
      for (int k = 0; k < 16; ++k) sum += exp2f((v[k] - mx) * l2e);
      #pragma unroll
      for (int off = 32; off > 0; off >>= 1) sum += __shfl_xor(sum, off);
      if (lane == 0) {
        smStat[(w * 8 + j) * 2]     = mx;
        smStat[(w * 8 + j) * 2 + 1] = 1.f / sum;
      }
    }
  }
  __syncthreads();
  const int   arow = tid >> 3;          // row this thread stages every step
  const float am   = smStat[arow * 2];
  const float ail  = smStat[arow * 2 + 1];
  __syncthreads();                       // stats in regs; smem now reusable

  // ---- pass 2 ----
  const int wm = w >> 2, wn = w & 3;    // wave tile 32x64
  const u16* Vb = VWT + (long)bz * P_ * S_;
  const int ac8 = tid & 7;              // A chunk (global, unswizzled)

  auto stageB = [&](int buf, int k0) {
    char* dB = smem + buf * SZB + 8192;
    #pragma unroll
    for (int i = 0; i < 4; ++i) {
      int cid = i * 512 + tid;
      int row = cid >> 3;
      int c   = (cid & 7) ^ (row & 7);
      gld_lds16(Vb + (size_t)row * S_ + k0 + c * 8, dB + cid * 16);
    }
  };
  auto writeA = [&](int buf, u16x8 raw) {
    u16x8 pv;
    #pragma unroll
    for (int j = 0; j < 8; ++j)
      pv[j] = f2h(exp2f((h2f(raw[j]) - am) * l2e) * ail);
    int c = ac8 ^ (arow & 7);
    *(u16x8*)(smem + buf * SZB + (arow * 8 + c) * 16) = pv;
  };

  f32x4 acc[2][4] = {};

  // prologue: stage tile 0
  {
    u16x8 a0 = *(const u16x8*)(sb + (size_t)arow * S_ + ac8 * 8);
    __builtin_amdgcn_sched_barrier(0);
    stageB(0, 0);
    __builtin_amdgcn_sched_barrier(0);
    asm volatile("s_waitcnt vmcnt(4)" ::: "memory");   // A landed
    writeA(0, a0);
    asm volatile("s_waitcnt vmcnt(0) lgkmcnt(0)" ::: "memory");
    __builtin_amdgcn_s_barrier();
  }

  for (int t = 0; t < 16; ++t) {
    const int cur = t & 1;
    const char* lA = smem + cur * SZB;
    const char* lB = lA + 8192;

    u16x8 anx;
    if (t < 15) {
      anx = *(const u16x8*)(sb + (size_t)arow * S_ + (t + 1) * 64 + ac8 * 8);
      __builtin_amdgcn_sched_barrier(0);
      stageB(cur ^ 1, (t + 1) * 64);
      __builtin_amdgcn_sched_barrier(0);
    }

    #pragma unroll
    for (int kk = 0; kk < 2; ++kk) {
      f16x8 af[2], bfv[4];
      #pragma unroll
      for (int m = 0; m < 2; ++m) {
        int row = wm * 32 + m * 16 + (lane & 15);
        int cp  = (kk * 4 + (lane >> 4)) ^ (row & 7);
        af[m] = *(const f16x8*)(lA + ((row * 8 + cp) << 4));
      }
      #pragma unroll
      for (int n = 0; n < 4; ++n) {
        int row = wn * 64 + n * 16 + (lane & 15);
        int cp  = (kk * 4 + (lane >> 4)) ^ (row & 7);
        bfv[n] = *(const f16x8*)(lB + ((row * 8 + cp) << 4));
      }
      __builtin_amdgcn_s_setprio(1);
      #pragma unroll
      for (int m = 0; m < 2; ++m)
        #pragma unroll
        for (int n = 0; n < 4; ++n)
          acc[m][n] = __builtin_amdgcn_mfma_f32_16x16x32_f16(af[m], bfv[n], acc[m][n], 0, 0, 0);
      __builtin_amdgcn_s_setprio(0);
    }

    if (t < 15) {
      asm volatile("s_waitcnt vmcnt(4)" ::: "memory");   // anx landed
      writeA(cur ^ 1, anx);
      asm volatile("s_waitcnt vmcnt(0) lgkmcnt(0)" ::: "memory");
      __builtin_amdgcn_s_barrier();
    }
  }

  // epilogue
  const int lr = lane & 15, hi = lane >> 4;
  const int row0 = q0 + wm * 32;
  const int col0 = wn * 64;
  float bv[4];
  #pragma unroll
  for (int n = 0; n < 4; ++n) bv[n] = bias[col0 + n * 16 + lr];
  #pragma unroll
  for (int m = 0; m < 2; ++m) {
    #pragma unroll
    for (int i = 0; i < 4; ++i) {
      int r = row0 + m * 16 + (hi << 2) + i;
      #pragma unroll
      for (int n = 0; n < 4; ++n)
        ob[(size_t)r * P_ + col0 + n * 16 + lr] = acc[m][n][i] + bv[n];
    }
  }
}

// ---------------------------------------------------------------------------
// VW GEMM (round-3 structure): C[MxN] = A[MxK]*B[NxK]^T, f16.
// ---------------------------------------------------------------------------
template<int KK, int BM, int BN, int NW, int WNS>
__global__ __launch_bounds__(NW * 64, 1) void gemm_nt_small(
    const u16* __restrict__ A, const u16* __restrict__ Bm,
    u16* __restrict__ C, long sAb, long sBb, long sCb, int LDC) {
  constexpr int T   = NW * 64;
  constexpr int WMS = NW / WNS;
  constexpr int MF  = BM / (WMS * 16);
  constexpr int NF  = BN / (WNS * 16);
  constexpr int LA  = BM * 8 / T;
  constexpr int LB  = BN * 8 / T;
  constexpr int SZ  = (BM + BN) * 128;
  constexpr int NT  = KK / 64;

  extern __shared__ __align__(16) char smem[];
  const int tid  = threadIdx.x;
  const int lane = tid & 63;
  const int w    = tid >> 6;
  const int wm   = w / WNS;
  const int wn   = w % WNS;
  const int lr   = lane & 15;
  const int hi   = lane >> 4;

  const int bz = blockIdx.z;
  const int I0 = blockIdx.y * BM;
  const int J0 = blockIdx.x * BN;
  const u16* Ab = A  + (long)bz * sAb;
  const u16* Bb = Bm + (long)bz * sBb;

  auto stage = [&](int buf, int k0) {
    char* sA = smem + buf * SZ;
    char* sB = sA + BM * 128;
    #pragma unroll
    for (int i = 0; i < LA; ++i) {
      int cid = i * T + tid;
      int row = cid >> 3;
      int c   = (cid & 7) ^ (row & 7);
      gld_lds16(Ab + (size_t)(I0 + row) * KK + k0 + c * 8, sA + cid * 16);
    }
    #pragma unroll
    for (int i = 0; i < LB; ++i) {
      int cid = i * T + tid;
      int row = cid >> 3;
      int c   = (cid & 7) ^ (row & 7);
      gld_lds16(Bb + (size_t)(J0 + row) * KK + k0 + c * 8, sB + cid * 16);
    }
  };

  f32x4 acc[MF][NF] = {};
  stage(0, 0);
  for (int t = 0; t < NT; ++t) {
    const char* lA = smem + (t & 1) * SZ;
    const char* lB = lA + BM * 128;
    if (t + 1 < NT) {
      stage((t + 1) & 1, (t + 1) * 64);
      asm volatile("s_waitcnt vmcnt(%0)" :: "i"(LA + LB) : "memory");
    } else {
      asm volatile("s_waitcnt vmcnt(0)" ::: "memory");
    }
    __builtin_amdgcn_s_barrier();
    __builtin_amdgcn_sched_barrier(0);
    #pragma unroll
    for (int kk = 0; kk < 2; ++kk) {
      f16x8 af[MF], bfv[NF];
      #pragma unroll
      for (int m = 0; m < MF; ++m) {
        int row = wm * (MF * 16) + m * 16 + lr;
        int cp  = (kk * 4 + hi) ^ (row & 7);
        af[m] = *(const f16x8*)(lA + ((row * 8 + cp) << 4));
      }
      #pragma unroll
      for (int n = 0; n < NF; ++n) {
        int row = wn * (NF * 16) + n * 16 + lr;
        int cp  = (kk * 4 + hi) ^ (row & 7);
        bfv[n] = *(const f16x8*)(lB + ((row * 8 + cp) << 4));
      }
      __builtin_amdgcn_s_setprio(1);
      #pragma unroll
      for (int m = 0; m < MF; ++m)
        #pragma unroll
        for (int n = 0; n < NF; ++n)
          acc[m][n] = __builtin_amdgcn_mfma_f32_16x16x32_f16(af[m], bfv[n], acc[m][n], 0, 0, 0);
      __builtin_amdgcn_s_setprio(0);
    }
    __builtin_amdgcn_sched_barrier(0);
    __builtin_amdgcn_s_barrier();
  }

  const int row0 = I0 + wm * (MF * 16);
  const int col0 = J0 + wn * (NF * 16);
  #pragma unroll
  for (int m = 0; m < MF; ++m)
    #pragma unroll
    for (int i = 0; i < 4; ++i) {
      int r = row0 + m * 16 + (hi << 2) + i;
      #pragma unroll
      for (int n = 0; n < NF; ++n)
        C[(long)bz * sCb + (size_t)r * LDC + col0 + n * 16 + lr] = f2h(acc[m][n][i]);
    }
}

// ---------------------------------------------------------------------------
extern "C" void kernel_launch(void* const* d_in, const int* in_sizes, int n_in,
                              void* d_out, int out_size, void* d_ws, size_t ws_size,
                              hipStream_t stream) {
  const float* data = (const float*)d_in[0];   // [16][1024][512]
  const float* W    = (const float*)d_in[1];   // [256][512]
  const float* bias = (const float*)d_in[2];   // [256]
  float* out = (float*)d_out;                  // [16][2048][256]
  char*  ws  = (char*)d_ws;

  const size_t MB = 1024 * 1024;
  u16* dataH   = (u16*)(ws);                   // 16 MB  [B][S][D] f16
  u16* Wh      = (u16*)(ws + 16 * MB);         // 256 KB [P][D] f16
  u16* scoresH = (u16*)(ws + 17 * MB);         // 32 MB  [B][S][S] f16
  u16* VWT     = (u16*)(ws + 49 * MB);         // 8 MB   [B][P][S] f16

  const float scale = 0.04419417382415922f;    // 1/sqrt(512)

  constexpr int SMEM_QK   = 4 * 32768;                 // 128 KB
  constexpr int SMEM_SMPV = 2 * (8192 + 32768);        // 80 KB
  constexpr int SMEM_VW   = 2 * (64 + 256) * 128;      // 80 KB

  (void)hipFuncSetAttribute((const void*)&qk_pipe,
                      hipFuncAttributeMaxDynamicSharedMemorySize, SMEM_QK);
  (void)hipFuncSetAttribute((const void*)&smpv_kernel,
                      hipFuncAttributeMaxDynamicSharedMemorySize, SMEM_SMPV);
  (void)hipFuncSetAttribute((const void*)&gemm_nt_small<512, 64, 256, 2, 2>,
                      hipFuncAttributeMaxDynamicSharedMemorySize, SMEM_VW);

  convert_f16_kernel<<<2048, 256, 0, stream>>>(data, dataH, (long)B_ * S_ * D_ / 4);
  convert_f16_kernel<<<64, 256, 0, stream>>>(W, Wh, (long)P_ * D_ / 4);

  // VWT[b] = Wh (256x512) @ dataH[b]^T -> [256][1024] f16
  gemm_nt_small<512, 64, 256, 2, 2><<<dim3(4, 4, 16), 128, SMEM_VW, stream>>>(
      Wh, dataH, VWT, 0L, (long)S_ * D_, (long)P_ * S_, S_);

  // scoresH[b] = scale * dataH[b] @ dataH[b]^T -> [1024][1024] f16
  qk_pipe<<<dim3(4, 4, 16), 512, SMEM_QK, stream>>>(dataH, scoresH, scale);

  // out[b][:S] = softmax(scoresH[b]) @ VWT[b]^T + bias; tail rows zeroed
  smpv_kernel<<<dim3(1, 32, 16), 512, SMEM_SMPV, stream>>>(
      scoresH, VWT, out, bias);
}

// Round 6
// 91.374 us; speedup vs baseline: 1.0319x; 1.0319x over previous
//
#include <hip/hip_runtime.h>
#include <cstdint>
#include <cstddef>

// Problem constants
#define B_    16
#define S_    1024
#define D_    512
#define P_    256
#define MAXS_ 2048

typedef unsigned short u16;
typedef unsigned int   u32;
typedef _Float16 f16;
typedef _Float16 f16x8 __attribute__((ext_vector_type(8)));
typedef float  f32x4  __attribute__((ext_vector_type(4)));
typedef unsigned short u16x4 __attribute__((ext_vector_type(4)));
typedef unsigned short u16x8 __attribute__((ext_vector_type(8)));

__device__ __forceinline__ void gld_lds16(const void* g, void* l) {
  __builtin_amdgcn_global_load_lds(
      (const __attribute__((address_space(1))) u32*)g,
      (__attribute__((address_space(3))) u32*)l, 16, 0, 0);
}

__device__ __forceinline__ u16 f2h(float f) {
  return __builtin_bit_cast(u16, (f16)f);
}
__device__ __forceinline__ float h2f(u16 h) {
  return (float)__builtin_bit_cast(f16, h);
}

// ---------------------------------------------------------------------------
// f32 -> f16 convert (data, W)
// ---------------------------------------------------------------------------
__global__ void convert_f16_kernel(const float* __restrict__ src, u16* __restrict__ dst, long n4) {
  long stride = (long)gridDim.x * blockDim.x;
  for (long i = (long)blockIdx.x * blockDim.x + threadIdx.x; i < n4; i += stride) {
    float4 v = ((const float4*)src)[i];
    u16x4 o;
    o[0] = f2h(v.x); o[1] = f2h(v.y); o[2] = f2h(v.z); o[3] = f2h(v.w);
    ((u16x4*)dst)[i] = o;
  }
}

// ---------------------------------------------------------------------------
// QK^T, slot-pipelined (unchanged from round 5 — verified working).
// ---------------------------------------------------------------------------
__global__ __launch_bounds__(512, 2) void qk_pipe(
    const u16* __restrict__ A, u16* __restrict__ Cout, float scale) {
  extern __shared__ __align__(16) char smem[];   // 4 * 32768
  const int tid  = threadIdx.x;
  const int lane = tid & 63;
  const int w    = tid >> 6;
  const int wm   = w >> 2;        // 0..1
  const int wn   = w & 3;         // 0..3
  const int lr   = lane & 15;
  const int hi   = lane >> 4;

  const int bz = blockIdx.z;
  const int I0 = blockIdx.y * 256;
  const int J0 = blockIdx.x * 256;
  const u16* Ab = A + (long)bz * (S_ * D_);

  auto stageP = [&](int s, int part) {
    if (s >= 16) return;
    char* dst = smem + (s & 3) * 32768 + part * 16384;
    const int base = part ? J0 : I0;
    const int k0 = s * 32;
    #pragma unroll
    for (int i = 0; i < 2; ++i) {
      int cid   = i * 512 + tid;
      int inner = cid >> 2;
      int c     = (cid & 3) ^ ((inner >> 1) & 3);
      gld_lds16(Ab + (size_t)(base + inner) * D_ + k0 + c * 8, dst + cid * 16);
    }
  };

  f32x4 acc[8][4] = {};

  stageP(0, 0); stageP(0, 1);
  stageP(1, 0); stageP(1, 1);
  stageP(2, 0); stageP(2, 1);
  asm volatile("s_waitcnt vmcnt(8)" ::: "memory");
  __builtin_amdgcn_s_barrier();

  for (int s = 0; s < 16; ++s) {
    const char* sl = smem + (s & 3) * 32768;
    f16x8 bf[4];
    // ---- phase 0 ----
    {
      f16x8 af[4];
      #pragma unroll
      for (int mq = 0; mq < 4; ++mq) {
        int row = wm * 128 + mq * 16 + lr;
        int cp  = hi ^ ((row >> 1) & 3);
        af[mq] = *(const f16x8*)(sl + row * 64 + cp * 16);
      }
      #pragma unroll
      for (int n = 0; n < 4; ++n) {
        int row = wn * 64 + n * 16 + lr;
        int cp  = hi ^ ((row >> 1) & 3);
        bf[n] = *(const f16x8*)(sl + 16384 + row * 64 + cp * 16);
      }
      stageP(s + 3, 0);
      __builtin_amdgcn_s_barrier();
      asm volatile("s_waitcnt lgkmcnt(0)" ::: "memory");
      __builtin_amdgcn_sched_barrier(0);
      __builtin_amdgcn_s_setprio(1);
      #pragma unroll
      for (int mq = 0; mq < 4; ++mq)
        #pragma unroll
        for (int n = 0; n < 4; ++n)
          acc[mq][n] = __builtin_amdgcn_mfma_f32_16x16x32_f16(af[mq], bf[n], acc[mq][n], 0, 0, 0);
      __builtin_amdgcn_s_setprio(0);
      __builtin_amdgcn_s_barrier();
    }
    // ---- phase 1 ----
    {
      f16x8 af[4];
      #pragma unroll
      for (int mq = 0; mq < 4; ++mq) {
        int row = wm * 128 + 64 + mq * 16 + lr;
        int cp  = hi ^ ((row >> 1) & 3);
        af[mq] = *(const f16x8*)(sl + row * 64 + cp * 16);
      }
      stageP(s + 3, 1);
      __builtin_amdgcn_s_barrier();
      asm volatile("s_waitcnt lgkmcnt(0)" ::: "memory");
      __builtin_amdgcn_sched_barrier(0);
      __builtin_amdgcn_s_setprio(1);
      #pragma unroll
      for (int mq = 0; mq < 4; ++mq)
        #pragma unroll
        for (int n = 0; n < 4; ++n)
          acc[4 + mq][n] = __builtin_amdgcn_mfma_f32_16x16x32_f16(af[mq], bf[n], acc[4 + mq][n], 0, 0, 0);
      __builtin_amdgcn_s_setprio(0);
      if (s <= 12)      asm volatile("s_waitcnt vmcnt(8)" ::: "memory");
      else if (s == 13) asm volatile("s_waitcnt vmcnt(4)" ::: "memory");
      else if (s == 14) asm volatile("s_waitcnt vmcnt(0)" ::: "memory");
      __builtin_amdgcn_s_barrier();
    }
  }

  u16* Cb = Cout + (long)bz * S_ * S_;
  const int row0 = I0 + wm * 128;
  const int col0 = J0 + wn * 64;
  #pragma unroll
  for (int m = 0; m < 8; ++m) {
    #pragma unroll
    for (int i = 0; i < 4; ++i) {
      int r = row0 + m * 16 + (hi << 2) + i;
      #pragma unroll
      for (int n = 0; n < 4; ++n) {
        int c = col0 + n * 16 + lr;
        Cb[(size_t)r * S_ + c] = f2h(acc[m][n][i] * scale);
      }
    }
  }
}

// ---------------------------------------------------------------------------
// Row stats: scores [16384][1024] f16 -> (max, 1/sumexp) float2 per row.
// One wave per row.
// ---------------------------------------------------------------------------
__global__ __launch_bounds__(256) void stats_kernel(
    const u16* __restrict__ scores, float2* __restrict__ rowstat) {
  const int lane = threadIdx.x & 63;
  const int wv   = threadIdx.x >> 6;
  const long row = (long)blockIdx.x * 4 + wv;
  const u16* src = scores + row * S_;

  u16x8 a0 = *(const u16x8*)&src[lane * 16];
  u16x8 a1 = *(const u16x8*)&src[lane * 16 + 8];
  float v[16];
  #pragma unroll
  for (int j = 0; j < 8; ++j) { v[j] = h2f(a0[j]); v[8 + j] = h2f(a1[j]); }

  float mx = v[0];
  #pragma unroll
  for (int j = 1; j < 16; ++j) mx = fmaxf(mx, v[j]);
  #pragma unroll
  for (int off = 32; off > 0; off >>= 1)
    mx = fmaxf(mx, __shfl_xor(mx, off));

  const float l2e = 1.4426950408889634f;
  float sum = 0.f;
  #pragma unroll
  for (int j = 0; j < 16; ++j) sum += exp2f((v[j] - mx) * l2e);
  #pragma unroll
  for (int off = 32; off > 0; off >>= 1)
    sum += __shfl_xor(sum, off);

  if (lane == 0) rowstat[row] = make_float2(mx, 1.f / sum);
}

// ---------------------------------------------------------------------------
// Fused single-pass PV: out[b][:S] = softmax(scores[b]) @ VWT[b]^T + bias.
//   Block 64 q-rows x 256 P, 4 waves 1M x 4N (wave tile 64x64, MF=NF=4:
//   16 b128 per 32 MFMA -> near MFMA/LDS balance). A-path: reg-load scores,
//   exp2((s-m)*l2e)*inv_l, swizzled ds_write (issue-early/write-late, T14).
//   B = VWT via gld_lds, double-buffered. LDS = 2*8K (A) + 2*32K (B) = 80 KB
//   -> 2 blocks/CU for cross-block latency overlap. Tail yt>=16 zero-fills.
// ---------------------------------------------------------------------------
__global__ __launch_bounds__(256, 2) void pv_kernel(
    const u16* __restrict__ scores, const u16* __restrict__ VWT,
    const float2* __restrict__ rowstat,
    float* __restrict__ out, const float* __restrict__ bias) {
  extern __shared__ __align__(16) char smem[];   // 81920 bytes
  const int tid  = threadIdx.x;
  const int lane = tid & 63;
  const int wn   = tid >> 6;          // 0..3 (N split)
  const int bz = blockIdx.z;
  const int yt = blockIdx.y;

  float* ob = out + (long)bz * MAXS_ * P_;
  if (yt >= 16) {                     // zero tail rows S_..2S_-1
    float4* o = (float4*)(ob + (size_t)yt * 64 * P_);
    for (int i = tid; i < 64 * P_ / 4; i += 256)
      o[i] = make_float4(0.f, 0.f, 0.f, 0.f);
    return;
  }

  const int q0 = yt * 64;
  const u16* sb = scores + ((long)bz * S_ + q0) * S_;
  const u16* Vb = VWT + (long)bz * P_ * S_;

  const int arow = tid >> 2;          // 0..63 (4 threads per q-row)
  const int ac   = tid & 3;           // 32B (16-col) group within 64-col tile
  float2 st = rowstat[(long)bz * S_ + q0 + arow];
  const float am = st.x, ail = st.y;
  const float l2e = 1.4426950408889634f;

  auto stageB = [&](int t) {          // 8 gld_lds16 per thread
    char* dB = smem + 16384 + (t & 1) * 32768;
    const int k0 = t * 64;
    #pragma unroll
    for (int i = 0; i < 8; ++i) {
      int cid = i * 256 + tid;
      int row = cid >> 3;
      int c   = (cid & 7) ^ (row & 7);
      gld_lds16(Vb + (size_t)row * S_ + k0 + c * 8, dB + cid * 16);
    }
  };
  auto writeA = [&](int buf, u16x8 r0, u16x8 r1) {
    u16x8 p0, p1;
    #pragma unroll
    for (int j = 0; j < 8; ++j) {
      p0[j] = f2h(exp2f((h2f(r0[j]) - am) * l2e) * ail);
      p1[j] = f2h(exp2f((h2f(r1[j]) - am) * l2e) * ail);
    }
    int c0 = (ac * 2)     ^ (arow & 7);
    int c1 = (ac * 2 + 1) ^ (arow & 7);
    *(u16x8*)(smem + buf * 8192 + (arow * 8 + c0) * 16) = p0;
    *(u16x8*)(smem + buf * 8192 + (arow * 8 + c1) * 16) = p1;
  };

  f32x4 acc[4][4] = {};
  u16x8 a0, a1;

  // prologue: tile 0
  a0 = *(const u16x8*)(sb + (size_t)arow * S_ + ac * 16);
  a1 = *(const u16x8*)(sb + (size_t)arow * S_ + ac * 16 + 8);
  __builtin_amdgcn_sched_barrier(0);
  stageB(0);
  __builtin_amdgcn_sched_barrier(0);
  asm volatile("s_waitcnt vmcnt(0)" ::: "memory");
  writeA(0, a0, a1);
  asm volatile("s_waitcnt lgkmcnt(0)" ::: "memory");
  __builtin_amdgcn_s_barrier();

  for (int t = 0; t < 16; ++t) {
    const char* lA = smem + (t & 1) * 8192;
    const char* lB = smem + 16384 + (t & 1) * 32768;

    if (t < 15) {                     // issue next-tile loads before MFMA
      a0 = *(const u16x8*)(sb + (size_t)arow * S_ + (t + 1) * 64 + ac * 16);
      a1 = *(const u16x8*)(sb + (size_t)arow * S_ + (t + 1) * 64 + ac * 16 + 8);
      __builtin_amdgcn_sched_barrier(0);
      stageB(t + 1);
      __builtin_amdgcn_sched_barrier(0);
    }

    #pragma unroll
    for (int kk = 0; kk < 2; ++kk) {
      f16x8 af[4], bf[4];
      #pragma unroll
      for (int m = 0; m < 4; ++m) {
        int row = m * 16 + (lane & 15);
        int cp  = (kk * 4 + (lane >> 4)) ^ (row & 7);
        af[m] = *(const f16x8*)(lA + ((row * 8 + cp) << 4));
      }
      #pragma unroll
      for (int n = 0; n < 4; ++n) {
        int row = wn * 64 + n * 16 + (lane & 15);
        int cp  = (kk * 4 + (lane >> 4)) ^ (row & 7);
        bf[n] = *(const f16x8*)(lB + ((row * 8 + cp) << 4));
      }
      __builtin_amdgcn_s_setprio(1);
      #pragma unroll
      for (int m = 0; m < 4; ++m)
        #pragma unroll
        for (int n = 0; n < 4; ++n)
          acc[m][n] = __builtin_amdgcn_mfma_f32_16x16x32_f16(af[m], bf[n], acc[m][n], 0, 0, 0);
      __builtin_amdgcn_s_setprio(0);
    }

    if (t < 15) {
      asm volatile("s_waitcnt vmcnt(0)" ::: "memory");   // a + B(t+1) landed
      writeA((t + 1) & 1, a0, a1);
      asm volatile("s_waitcnt lgkmcnt(0)" ::: "memory");
      __builtin_amdgcn_s_barrier();
    }
  }

  // epilogue. C/D: col = lane&15, row = (lane>>4)*4 + reg.
  const int lr = lane & 15, hi = lane >> 4;
  const int col0 = wn * 64;
  float bv[4];
  #pragma unroll
  for (int n = 0; n < 4; ++n) bv[n] = bias[col0 + n * 16 + lr];
  #pragma unroll
  for (int m = 0; m < 4; ++m) {
    #pragma unroll
    for (int i = 0; i < 4; ++i) {
      int r = q0 + m * 16 + (hi << 2) + i;
      #pragma unroll
      for (int n = 0; n < 4; ++n)
        ob[(size_t)r * P_ + col0 + n * 16 + lr] = acc[m][n][i] + bv[n];
    }
  }
}

// ---------------------------------------------------------------------------
// VW GEMM (round-3 structure, unchanged): C[MxN] = A[MxK]*B[NxK]^T, f16.
// ---------------------------------------------------------------------------
template<int KK, int BM, int BN, int NW, int WNS>
__global__ __launch_bounds__(NW * 64, 1) void gemm_nt_small(
    const u16* __restrict__ A, const u16* __restrict__ Bm,
    u16* __restrict__ C, long sAb, long sBb, long sCb, int LDC) {
  constexpr int T   = NW * 64;
  constexpr int WMS = NW / WNS;
  constexpr int MF  = BM / (WMS * 16);
  constexpr int NF  = BN / (WNS * 16);
  constexpr int LA  = BM * 8 / T;
  constexpr int LB  = BN * 8 / T;
  constexpr int SZ  = (BM + BN) * 128;
  constexpr int NT  = KK / 64;

  extern __shared__ __align__(16) char smem[];
  const int tid  = threadIdx.x;
  const int lane = tid & 63;
  const int w    = tid >> 6;
  const int wm   = w / WNS;
  const int wn   = w % WNS;
  const int lr   = lane & 15;
  const int hi   = lane >> 4;

  const int bz = blockIdx.z;
  const int I0 = blockIdx.y * BM;
  const int J0 = blockIdx.x * BN;
  const u16* Ab = A  + (long)bz * sAb;
  const u16* Bb = Bm + (long)bz * sBb;

  auto stage = [&](int buf, int k0) {
    char* sA = smem + buf * SZ;
    char* sB = sA + BM * 128;
    #pragma unroll
    for (int i = 0; i < LA; ++i) {
      int cid = i * T + tid;
      int row = cid >> 3;
      int c   = (cid & 7) ^ (row & 7);
      gld_lds16(Ab + (size_t)(I0 + row) * KK + k0 + c * 8, sA + cid * 16);
    }
    #pragma unroll
    for (int i = 0; i < LB; ++i) {
      int cid = i * T + tid;
      int row = cid >> 3;
      int c   = (cid & 7) ^ (row & 7);
      gld_lds16(Bb + (size_t)(J0 + row) * KK + k0 + c * 8, sB + cid * 16);
    }
  };

  f32x4 acc[MF][NF] = {};
  stage(0, 0);
  for (int t = 0; t < NT; ++t) {
    const char* lA = smem + (t & 1) * SZ;
    const char* lB = lA + BM * 128;
    if (t + 1 < NT) {
      stage((t + 1) & 1, (t + 1) * 64);
      asm volatile("s_waitcnt vmcnt(%0)" :: "i"(LA + LB) : "memory");
    } else {
      asm volatile("s_waitcnt vmcnt(0)" ::: "memory");
    }
    __builtin_amdgcn_s_barrier();
    __builtin_amdgcn_sched_barrier(0);
    #pragma unroll
    for (int kk = 0; kk < 2; ++kk) {
      f16x8 af[MF], bfv[NF];
      #pragma unroll
      for (int m = 0; m < MF; ++m) {
        int row = wm * (MF * 16) + m * 16 + lr;
        int cp  = (kk * 4 + hi) ^ (row & 7);
        af[m] = *(const f16x8*)(lA + ((row * 8 + cp) << 4));
      }
      #pragma unroll
      for (int n = 0; n < NF; ++n) {
        int row = wn * (NF * 16) + n * 16 + lr;
        int cp  = (kk * 4 + hi) ^ (row & 7);
        bfv[n] = *(const f16x8*)(lB + ((row * 8 + cp) << 4));
      }
      __builtin_amdgcn_s_setprio(1);
      #pragma unroll
      for (int m = 0; m < MF; ++m)
        #pragma unroll
        for (int n = 0; n < NF; ++n)
          acc[m][n] = __builtin_amdgcn_mfma_f32_16x16x32_f16(af[m], bfv[n], acc[m][n], 0, 0, 0);
      __builtin_amdgcn_s_setprio(0);
    }
    __builtin_amdgcn_sched_barrier(0);
    __builtin_amdgcn_s_barrier();
  }

  const int row0 = I0 + wm * (MF * 16);
  const int col0 = J0 + wn * (NF * 16);
  #pragma unroll
  for (int m = 0; m < MF; ++m)
    #pragma unroll
    for (int i = 0; i < 4; ++i) {
      int r = row0 + m * 16 + (hi << 2) + i;
      #pragma unroll
      for (int n = 0; n < NF; ++n)
        C[(long)bz * sCb + (size_t)r * LDC + col0 + n * 16 + lr] = f2h(acc[m][n][i]);
    }
}

// ---------------------------------------------------------------------------
extern "C" void kernel_launch(void* const* d_in, const int* in_sizes, int n_in,
                              void* d_out, int out_size, void* d_ws, size_t ws_size,
                              hipStream_t stream) {
  const float* data = (const float*)d_in[0];   // [16][1024][512]
  const float* W    = (const float*)d_in[1];   // [256][512]
  const float* bias = (const float*)d_in[2];   // [256]
  float* out = (float*)d_out;                  // [16][2048][256]
  char*  ws  = (char*)d_ws;

  const size_t MB = 1024 * 1024;
  u16*    dataH   = (u16*)(ws);                // 16 MB  [B][S][D] f16
  u16*    Wh      = (u16*)(ws + 16 * MB);      // 256 KB [P][D] f16
  u16*    scoresH = (u16*)(ws + 17 * MB);      // 32 MB  [B][S][S] f16
  u16*    VWT     = (u16*)(ws + 49 * MB);      // 8 MB   [B][P][S] f16
  float2* rowstat = (float2*)(ws + 57 * MB);   // 128 KB [B][S] (m, 1/l)

  const float scale = 0.04419417382415922f;    // 1/sqrt(512)

  constexpr int SMEM_QK = 4 * 32768;             // 128 KB
  constexpr int SMEM_PV = 2 * 8192 + 2 * 32768;  // 80 KB
  constexpr int SMEM_VW = 2 * (64 + 256) * 128;  // 80 KB

  (void)hipFuncSetAttribute((const void*)&qk_pipe,
                      hipFuncAttributeMaxDynamicSharedMemorySize, SMEM_QK);
  (void)hipFuncSetAttribute((const void*)&pv_kernel,
                      hipFuncAttributeMaxDynamicSharedMemorySize, SMEM_PV);
  (void)hipFuncSetAttribute((const void*)&gemm_nt_small<512, 64, 256, 2, 2>,
                      hipFuncAttributeMaxDynamicSharedMemorySize, SMEM_VW);

  convert_f16_kernel<<<2048, 256, 0, stream>>>(data, dataH, (long)B_ * S_ * D_ / 4);
  convert_f16_kernel<<<64, 256, 0, stream>>>(W, Wh, (long)P_ * D_ / 4);

  // VWT[b] = Wh (256x512) @ dataH[b]^T -> [256][1024] f16
  gemm_nt_small<512, 64, 256, 2, 2><<<dim3(4, 4, 16), 128, SMEM_VW, stream>>>(
      Wh, dataH, VWT, 0L, (long)S_ * D_, (long)P_ * S_, S_);

  // scoresH[b] = scale * dataH[b] @ dataH[b]^T -> [1024][1024] f16
  qk_pipe<<<dim3(4, 4, 16), 512, SMEM_QK, stream>>>(dataH, scoresH, scale);

  // rowstat = per-row (max, 1/sumexp)
  stats_kernel<<<4096, 256, 0, stream>>>(scoresH, rowstat);

  // out[b][:S] = softmax(scoresH[b]) @ VWT[b]^T + bias; tail rows zeroed
  pv_kernel<<<dim3(1, 32, 16), 256, SMEM_PV, stream>>>(
      scoresH, VWT, rowstat, out, bias);
}

// Round 7
// 83.226 us; speedup vs baseline: 1.1329x; 1.0979x over previous
//
#include <hip/hip_runtime.h>
#include <cstdint>
#include <cstddef>

// Problem constants
#define B_    16
#define S_    1024
#define D_    512
#define P_    256
#define MAXS_ 2048

typedef unsigned short u16;
typedef unsigned int   u32;
typedef _Float16 f16;
typedef _Float16 f16x8 __attribute__((ext_vector_type(8)));
typedef float  f32x4  __attribute__((ext_vector_type(4)));
typedef unsigned short u16x4 __attribute__((ext_vector_type(4)));
typedef unsigned short u16x8 __attribute__((ext_vector_type(8)));

__device__ __forceinline__ void gld_lds16(const void* g, void* l) {
  __builtin_amdgcn_global_load_lds(
      (const __attribute__((address_space(1))) u32*)g,
      (__attribute__((address_space(3))) u32*)l, 16, 0, 0);
}

__device__ __forceinline__ u16 f2h(float f) {
  return __builtin_bit_cast(u16, (f16)f);
}
__device__ __forceinline__ float h2f(u16 h) {
  return (float)__builtin_bit_cast(f16, h);
}

// ---------------------------------------------------------------------------
// f32 -> f16 convert (data, W)
// ---------------------------------------------------------------------------
__global__ void convert_f16_kernel(const float* __restrict__ src, u16* __restrict__ dst, long n4) {
  long stride = (long)gridDim.x * blockDim.x;
  for (long i = (long)blockIdx.x * blockDim.x + threadIdx.x; i < n4; i += stride) {
    float4 v = ((const float4*)src)[i];
    u16x4 o;
    o[0] = f2h(v.x); o[1] = f2h(v.y); o[2] = f2h(v.z); o[3] = f2h(v.w);
    ((u16x4*)dst)[i] = o;
  }
}

// ---------------------------------------------------------------------------
// QK^T, slot-pipelined (unchanged from round 5/6 — frozen for attribution).
// ---------------------------------------------------------------------------
__global__ __launch_bounds__(512, 2) void qk_pipe(
    const u16* __restrict__ A, u16* __restrict__ Cout, float scale) {
  extern __shared__ __align__(16) char smem[];   // 4 * 32768
  const int tid  = threadIdx.x;
  const int lane = tid & 63;
  const int w    = tid >> 6;
  const int wm   = w >> 2;        // 0..1
  const int wn   = w & 3;         // 0..3
  const int lr   = lane & 15;
  const int hi   = lane >> 4;

  const int bz = blockIdx.z;
  const int I0 = blockIdx.y * 256;
  const int J0 = blockIdx.x * 256;
  const u16* Ab = A + (long)bz * (S_ * D_);

  auto stageP = [&](int s, int part) {
    if (s >= 16) return;
    char* dst = smem + (s & 3) * 32768 + part * 16384;
    const int base = part ? J0 : I0;
    const int k0 = s * 32;
    #pragma unroll
    for (int i = 0; i < 2; ++i) {
      int cid   = i * 512 + tid;
      int inner = cid >> 2;
      int c     = (cid & 3) ^ ((inner >> 1) & 3);
      gld_lds16(Ab + (size_t)(base + inner) * D_ + k0 + c * 8, dst + cid * 16);
    }
  };

  f32x4 acc[8][4] = {};

  stageP(0, 0); stageP(0, 1);
  stageP(1, 0); stageP(1, 1);
  stageP(2, 0); stageP(2, 1);
  asm volatile("s_waitcnt vmcnt(8)" ::: "memory");
  __builtin_amdgcn_s_barrier();

  for (int s = 0; s < 16; ++s) {
    const char* sl = smem + (s & 3) * 32768;
    f16x8 bf[4];
    // ---- phase 0 ----
    {
      f16x8 af[4];
      #pragma unroll
      for (int mq = 0; mq < 4; ++mq) {
        int row = wm * 128 + mq * 16 + lr;
        int cp  = hi ^ ((row >> 1) & 3);
        af[mq] = *(const f16x8*)(sl + row * 64 + cp * 16);
      }
      #pragma unroll
      for (int n = 0; n < 4; ++n) {
        int row = wn * 64 + n * 16 + lr;
        int cp  = hi ^ ((row >> 1) & 3);
        bf[n] = *(const f16x8*)(sl + 16384 + row * 64 + cp * 16);
      }
      stageP(s + 3, 0);
      __builtin_amdgcn_s_barrier();
      asm volatile("s_waitcnt lgkmcnt(0)" ::: "memory");
      __builtin_amdgcn_sched_barrier(0);
      __builtin_amdgcn_s_setprio(1);
      #pragma unroll
      for (int mq = 0; mq < 4; ++mq)
        #pragma unroll
        for (int n = 0; n < 4; ++n)
          acc[mq][n] = __builtin_amdgcn_mfma_f32_16x16x32_f16(af[mq], bf[n], acc[mq][n], 0, 0, 0);
      __builtin_amdgcn_s_setprio(0);
      __builtin_amdgcn_s_barrier();
    }
    // ---- phase 1 ----
    {
      f16x8 af[4];
      #pragma unroll
      for (int mq = 0; mq < 4; ++mq) {
        int row = wm * 128 + 64 + mq * 16 + lr;
        int cp  = hi ^ ((row >> 1) & 3);
        af[mq] = *(const f16x8*)(sl + row * 64 + cp * 16);
      }
      stageP(s + 3, 1);
      __builtin_amdgcn_s_barrier();
      asm volatile("s_waitcnt lgkmcnt(0)" ::: "memory");
      __builtin_amdgcn_sched_barrier(0);
      __builtin_amdgcn_s_setprio(1);
      #pragma unroll
      for (int mq = 0; mq < 4; ++mq)
        #pragma unroll
        for (int n = 0; n < 4; ++n)
          acc[4 + mq][n] = __builtin_amdgcn_mfma_f32_16x16x32_f16(af[mq], bf[n], acc[4 + mq][n], 0, 0, 0);
      __builtin_amdgcn_s_setprio(0);
      if (s <= 12)      asm volatile("s_waitcnt vmcnt(8)" ::: "memory");
      else if (s == 13) asm volatile("s_waitcnt vmcnt(4)" ::: "memory");
      else if (s == 14) asm volatile("s_waitcnt vmcnt(0)" ::: "memory");
      __builtin_amdgcn_s_barrier();
    }
  }

  u16* Cb = Cout + (long)bz * S_ * S_;
  const int row0 = I0 + wm * 128;
  const int col0 = J0 + wn * 64;
  #pragma unroll
  for (int m = 0; m < 8; ++m) {
    #pragma unroll
    for (int i = 0; i < 4; ++i) {
      int r = row0 + m * 16 + (hi << 2) + i;
      #pragma unroll
      for (int n = 0; n < 4; ++n) {
        int c = col0 + n * 16 + lr;
        Cb[(size_t)r * S_ + c] = f2h(acc[m][n][i] * scale);
      }
    }
  }
}

// ---------------------------------------------------------------------------
// Row stats: scores [16384][1024] f16 -> (max, 1/sumexp) float2 per row.
// ---------------------------------------------------------------------------
__global__ __launch_bounds__(256) void stats_kernel(
    const u16* __restrict__ scores, float2* __restrict__ rowstat) {
  const int lane = threadIdx.x & 63;
  const int wv   = threadIdx.x >> 6;
  const long row = (long)blockIdx.x * 4 + wv;
  const u16* src = scores + row * S_;

  u16x8 a0 = *(const u16x8*)&src[lane * 16];
  u16x8 a1 = *(const u16x8*)&src[lane * 16 + 8];
  float v[16];
  #pragma unroll
  for (int j = 0; j < 8; ++j) { v[j] = h2f(a0[j]); v[8 + j] = h2f(a1[j]); }

  float mx = v[0];
  #pragma unroll
  for (int j = 1; j < 16; ++j) mx = fmaxf(mx, v[j]);
  #pragma unroll
  for (int off = 32; off > 0; off >>= 1)
    mx = fmaxf(mx, __shfl_xor(mx, off));

  const float l2e = 1.4426950408889634f;
  float sum = 0.f;
  #pragma unroll
  for (int j = 0; j < 16; ++j) sum += exp2f((v[j] - mx) * l2e);
  #pragma unroll
  for (int off = 32; off > 0; off >>= 1)
    sum += __shfl_xor(sum, off);

  if (lane == 0) rowstat[row] = make_float2(mx, 1.f / sum);
}

// ---------------------------------------------------------------------------
// Fused single-pass PV: out[b][:S] = softmax(scores[b]) @ VWT[b]^T + bias.
//   Block = 32 q-rows x 256 P, 4 waves 1M x 4N (wave tile 32x64).
//   grid (1, 64, 16): yt<32 real (512 blocks = 2/CU real occupancy), yt>=32
//   zero-fill tail rows. LDS = A 2x4K + B 2x32K = 72 KB -> 2 blocks/CU ->
//   8 waves/CU overlap the per-tile drains (this was the round-6 failure:
//   1 real block/CU with full drains). A-path: reg-load scores, exp, swizzled
//   ds_write; counted vmcnt(8) lets the exp+write overlap B staging.
// ---------------------------------------------------------------------------
__global__ __launch_bounds__(256, 2) void pv_kernel(
    const u16* __restrict__ scores, const u16* __restrict__ VWT,
    const float2* __restrict__ rowstat,
    float* __restrict__ out, const float* __restrict__ bias) {
  extern __shared__ __align__(16) char smem[];   // 73728 bytes
  const int tid  = threadIdx.x;
  const int lane = tid & 63;
  const int wn   = tid >> 6;          // 0..3 (N split)
  const int bz = blockIdx.z;
  const int yt = blockIdx.y;

  float* ob = out + (long)bz * MAXS_ * P_;
  if (yt >= 32) {                     // zero tail rows 1024..2047
    float4* o = (float4*)(ob + (size_t)yt * 32 * P_);
    for (int i = tid; i < 32 * P_ / 4; i += 256)
      o[i] = make_float4(0.f, 0.f, 0.f, 0.f);
    return;
  }

  const int q0 = yt * 32;
  const u16* sb = scores + ((long)bz * S_ + q0) * S_;
  const u16* Vb = VWT + (long)bz * P_ * S_;

  const int arow = tid >> 3;          // 0..31 (8 threads per q-row)
  const int ac   = tid & 7;           // 16B chunk within the 64-col tile
  float2 st = rowstat[(long)bz * S_ + q0 + arow];
  const float am = st.x, ail = st.y;
  const float l2e = 1.4426950408889634f;

  auto stageB = [&](int t) {          // 8 gld_lds16 per thread (32 KB)
    char* dB = smem + 8192 + (t & 1) * 32768;
    const int k0 = t * 64;
    #pragma unroll
    for (int i = 0; i < 8; ++i) {
      int cid = i * 256 + tid;
      int row = cid >> 3;
      int c   = (cid & 7) ^ (row & 7);
      gld_lds16(Vb + (size_t)row * S_ + k0 + c * 8, dB + cid * 16);
    }
  };
  auto writeA = [&](int buf, u16x8 r0) {
    u16x8 p0;
    #pragma unroll
    for (int j = 0; j < 8; ++j)
      p0[j] = f2h(exp2f((h2f(r0[j]) - am) * l2e) * ail);
    int c = ac ^ (arow & 7);
    *(u16x8*)(smem + buf * 4096 + (arow * 8 + c) * 16) = p0;
  };

  f32x4 acc[2][4] = {};
  u16x8 anx;

  // prologue: tile 0
  anx = *(const u16x8*)(sb + (size_t)arow * S_ + ac * 8);
  __builtin_amdgcn_sched_barrier(0);
  stageB(0);
  __builtin_amdgcn_sched_barrier(0);
  asm volatile("s_waitcnt vmcnt(8)" ::: "memory");   // A-load (oldest) landed
  writeA(0, anx);
  asm volatile("s_waitcnt vmcnt(0) lgkmcnt(0)" ::: "memory");
  __builtin_amdgcn_s_barrier();

  for (int t = 0; t < 16; ++t) {
    const char* lA = smem + (t & 1) * 4096;
    const char* lB = smem + 8192 + (t & 1) * 32768;

    if (t < 15) {                     // issue next-tile loads before MFMA
      anx = *(const u16x8*)(sb + (size_t)arow * S_ + (t + 1) * 64 + ac * 8);
      __builtin_amdgcn_sched_barrier(0);
      stageB(t + 1);
      __builtin_amdgcn_sched_barrier(0);
    }

    #pragma unroll
    for (int kk = 0; kk < 2; ++kk) {
      f16x8 af[2], bf[4];
      #pragma unroll
      for (int m = 0; m < 2; ++m) {
        int row = m * 16 + (lane & 15);
        int cp  = (kk * 4 + (lane >> 4)) ^ (row & 7);
        af[m] = *(const f16x8*)(lA + ((row * 8 + cp) << 4));
      }
      #pragma unroll
      for (int n = 0; n < 4; ++n) {
        int row = wn * 64 + n * 16 + (lane & 15);
        int cp  = (kk * 4 + (lane >> 4)) ^ (row & 7);
        bf[n] = *(const f16x8*)(lB + ((row * 8 + cp) << 4));
      }
      __builtin_amdgcn_s_setprio(1);
      #pragma unroll
      for (int m = 0; m < 2; ++m)
        #pragma unroll
        for (int n = 0; n < 4; ++n)
          acc[m][n] = __builtin_amdgcn_mfma_f32_16x16x32_f16(af[m], bf[n], acc[m][n], 0, 0, 0);
      __builtin_amdgcn_s_setprio(0);
    }

    if (t < 15) {
      asm volatile("s_waitcnt vmcnt(8)" ::: "memory");   // next A landed
      writeA((t + 1) & 1, anx);
      asm volatile("s_waitcnt vmcnt(0) lgkmcnt(0)" ::: "memory");
      __builtin_amdgcn_s_barrier();
    }
  }

  // epilogue. C/D: col = lane&15, row = (lane>>4)*4 + reg.
  const int lr = lane & 15, hi = lane >> 4;
  const int col0 = wn * 64;
  float bv[4];
  #pragma unroll
  for (int n = 0; n < 4; ++n) bv[n] = bias[col0 + n * 16 + lr];
  #pragma unroll
  for (int m = 0; m < 2; ++m) {
    #pragma unroll
    for (int i = 0; i < 4; ++i) {
      int r = q0 + m * 16 + (hi << 2) + i;
      #pragma unroll
      for (int n = 0; n < 4; ++n)
        ob[(size_t)r * P_ + col0 + n * 16 + lr] = acc[m][n][i] + bv[n];
    }
  }
}

// ---------------------------------------------------------------------------
// VW GEMM: C[MxN] = A[MxK]*B[NxK]^T, f16 (flexible tile template).
// ---------------------------------------------------------------------------
template<int KK, int BM, int BN, int NW, int WNS>
__global__ __launch_bounds__(NW * 64, 2) void gemm_nt_small(
    const u16* __restrict__ A, const u16* __restrict__ Bm,
    u16* __restrict__ C, long sAb, long sBb, long sCb, int LDC) {
  constexpr int T   = NW * 64;
  constexpr int WMS = NW / WNS;
  constexpr int MF  = BM / (WMS * 16);
  constexpr int NF  = BN / (WNS * 16);
  constexpr int LA  = BM * 8 / T;
  constexpr int LB  = BN * 8 / T;
  constexpr int SZ  = (BM + BN) * 128;
  constexpr int NT  = KK / 64;

  extern __shared__ __align__(16) char smem[];
  const int tid  = threadIdx.x;
  const int lane = tid & 63;
  const int w    = tid >> 6;
  const int wm   = w / WNS;
  const int wn   = w % WNS;
  const int lr   = lane & 15;
  const int hi   = lane >> 4;

  const int bz = blockIdx.z;
  const int I0 = blockIdx.y * BM;
  const int J0 = blockIdx.x * BN;
  const u16* Ab = A  + (long)bz * sAb;
  const u16* Bb = Bm + (long)bz * sBb;

  auto stage = [&](int buf, int k0) {
    char* sA = smem + buf * SZ;
    char* sB = sA + BM * 128;
    #pragma unroll
    for (int i = 0; i < LA; ++i) {
      int cid = i * T + tid;
      int row = cid >> 3;
      int c   = (cid & 7) ^ (row & 7);
      gld_lds16(Ab + (size_t)(I0 + row) * KK + k0 + c * 8, sA + cid * 16);
    }
    #pragma unroll
    for (int i = 0; i < LB; ++i) {
      int cid = i * T + tid;
      int row = cid >> 3;
      int c   = (cid & 7) ^ (row & 7);
      gld_lds16(Bb + (size_t)(J0 + row) * KK + k0 + c * 8, sB + cid * 16);
    }
  };

  f32x4 acc[MF][NF] = {};
  stage(0, 0);
  for (int t = 0; t < NT; ++t) {
    const char* lA = smem + (t & 1) * SZ;
    const char* lB = lA + BM * 128;
    if (t + 1 < NT) {
      stage((t + 1) & 1, (t + 1) * 64);
      asm volatile("s_waitcnt vmcnt(%0)" :: "i"(LA + LB) : "memory");
    } else {
      asm volatile("s_waitcnt vmcnt(0)" ::: "memory");
    }
    __builtin_amdgcn_s_barrier();
    __builtin_amdgcn_sched_barrier(0);
    #pragma unroll
    for (int kk = 0; kk < 2; ++kk) {
      f16x8 af[MF], bfv[NF];
      #pragma unroll
      for (int m = 0; m < MF; ++m) {
        int row = wm * (MF * 16) + m * 16 + lr;
        int cp  = (kk * 4 + hi) ^ (row & 7);
        af[m] = *(const f16x8*)(lA + ((row * 8 + cp) << 4));
      }
      #pragma unroll
      for (int n = 0; n < NF; ++n) {
        int row = wn * (NF * 16) + n * 16 + lr;
        int cp  = (kk * 4 + hi) ^ (row & 7);
        bfv[n] = *(const f16x8*)(lB + ((row * 8 + cp) << 4));
      }
      __builtin_amdgcn_s_setprio(1);
      #pragma unroll
      for (int m = 0; m < MF; ++m)
        #pragma unroll
        for (int n = 0; n < NF; ++n)
          acc[m][n] = __builtin_amdgcn_mfma_f32_16x16x32_f16(af[m], bfv[n], acc[m][n], 0, 0, 0);
      __builtin_amdgcn_s_setprio(0);
    }
    __builtin_amdgcn_sched_barrier(0);
    __builtin_amdgcn_s_barrier();
  }

  const int row0 = I0 + wm * (MF * 16);
  const int col0 = J0 + wn * (NF * 16);
  #pragma unroll
  for (int m = 0; m < MF; ++m)
    #pragma unroll
    for (int i = 0; i < 4; ++i) {
      int r = row0 + m * 16 + (hi << 2) + i;
      #pragma unroll
      for (int n = 0; n < NF; ++n)
        C[(long)bz * sCb + (size_t)r * LDC + col0 + n * 16 + lr] = f2h(acc[m][n][i]);
    }
}

// ---------------------------------------------------------------------------
extern "C" void kernel_launch(void* const* d_in, const int* in_sizes, int n_in,
                              void* d_out, int out_size, void* d_ws, size_t ws_size,
                              hipStream_t stream) {
  const float* data = (const float*)d_in[0];   // [16][1024][512]
  const float* W    = (const float*)d_in[1];   // [256][512]
  const float* bias = (const float*)d_in[2];   // [256]
  float* out = (float*)d_out;                  // [16][2048][256]
  char*  ws  = (char*)d_ws;

  const size_t MB = 1024 * 1024;
  u16*    dataH   = (u16*)(ws);                // 16 MB  [B][S][D] f16
  u16*    Wh      = (u16*)(ws + 16 * MB);      // 256 KB [P][D] f16
  u16*    scoresH = (u16*)(ws + 17 * MB);      // 32 MB  [B][S][S] f16
  u16*    VWT     = (u16*)(ws + 49 * MB);      // 8 MB   [B][P][S] f16
  float2* rowstat = (float2*)(ws + 57 * MB);   // 128 KB [B][S] (m, 1/l)

  const float scale = 0.04419417382415922f;    // 1/sqrt(512)

  constexpr int SMEM_QK = 4 * 32768;             // 128 KB
  constexpr int SMEM_PV = 2 * 4096 + 2 * 32768;  // 72 KB
  constexpr int SMEM_VW = 2 * (64 + 128) * 128;  // 48 KB

  (void)hipFuncSetAttribute((const void*)&qk_pipe,
                      hipFuncAttributeMaxDynamicSharedMemorySize, SMEM_QK);
  (void)hipFuncSetAttribute((const void*)&pv_kernel,
                      hipFuncAttributeMaxDynamicSharedMemorySize, SMEM_PV);
  (void)hipFuncSetAttribute((const void*)&gemm_nt_small<512, 64, 128, 4, 2>,
                      hipFuncAttributeMaxDynamicSharedMemorySize, SMEM_VW);

  convert_f16_kernel<<<2048, 256, 0, stream>>>(data, dataH, (long)B_ * S_ * D_ / 4);
  convert_f16_kernel<<<64, 256, 0, stream>>>(W, Wh, (long)P_ * D_ / 4);

  // VWT[b] = Wh (256x512) @ dataH[b]^T -> [256][1024] f16
  // BM=64 BN=128 NW=4 WNS=2: wave 32x64, grid 512 blocks, 3 blocks/CU by LDS
  gemm_nt_small<512, 64, 128, 4, 2><<<dim3(8, 4, 16), 256, SMEM_VW, stream>>>(
      Wh, dataH, VWT, 0L, (long)S_ * D_, (long)P_ * S_, S_);

  // scoresH[b] = scale * dataH[b] @ dataH[b]^T -> [1024][1024] f16
  qk_pipe<<<dim3(4, 4, 16), 512, SMEM_QK, stream>>>(dataH, scoresH, scale);

  // rowstat = per-row (max, 1/sumexp)
  stats_kernel<<<4096, 256, 0, stream>>>(scoresH, rowstat);

  // out[b][:S] = softmax(scoresH[b]) @ VWT[b]^T + bias; tail rows zeroed
  pv_kernel<<<dim3(1, 64, 16), 256, SMEM_PV, stream>>>(
      scoresH, VWT, rowstat, out, bias);
}